// Round 5
// baseline (277.926 us; speedup 1.0000x reference)
//
#include <hip/hip_runtime.h>
#include <hip/hip_bf16.h>
#include <stdint.h>

#define T_SEQ 2048
#define DIMSZ 1024
#define NH    16
#define HDIM  64
#define NBATCH 2
#define ATT_SCALE 0.12f

typedef __attribute__((ext_vector_type(8))) __bf16 bf16x8;
typedef __attribute__((ext_vector_type(4))) float f32x4;

#define GLOAD_LDS16(gp, lp)                                                            \
  __builtin_amdgcn_global_load_lds((const __attribute__((address_space(1))) void*)(gp),\
                                   (__attribute__((address_space(3))) void*)(lp),      \
                                   16, 0, 0)

__device__ __forceinline__ ushort f2bf(float f) {
  union { float f; uint32_t u; } v; v.f = f;
  uint32_t u = v.u;
  uint32_t r = (u + 0x7FFFu + ((u >> 16) & 1u)) >> 16;
  return (ushort)r;
}

// paired f32->bf16 (compiler fuses the two casts into v_cvt_pk_bf16_f32)
__device__ __forceinline__ uint32_t pk2(float a, float b) {
  union { __hip_bfloat162 h; uint32_t u; } cv;
  cv.h = __hip_bfloat162(__float2bfloat16(a), __float2bfloat16(b));
  return cv.u;
}

// ---------------- f32 -> bf16 convert (vectorized) ----------------
__global__ __launch_bounds__(256) void conv_bf16_k(const float* __restrict__ in,
                                                   ushort* __restrict__ out, int n) {
  int i = (blockIdx.x * 256 + threadIdx.x) * 4;
  if (i >= n) return;
  float4 v = *(const float4*)(in + i);
  ushort4 o;
  o.x = f2bf(v.x); o.y = f2bf(v.y); o.z = f2bf(v.z); o.w = f2bf(v.w);
  *(ushort4*)(out + i) = o;
}

// ---------------- RoPE tables: cos/sin (T x 32) ----------------
__global__ __launch_bounds__(256) void rope_tab_k(float* __restrict__ ctab,
                                                  float* __restrict__ stab) {
  int idx = blockIdx.x * 256 + threadIdx.x;  // t*32 + j
  if (idx >= T_SEQ * 32) return;
  int j = idx & 31, t = idx >> 5;
  float c = 1.f, s = 0.f;
  if (j < 16) {
    float inv = powf(1024.0f, -(float)j / 15.0f);  // (1/1024)^(j/15)
    float th = (float)t * inv;
    c = cosf(th);
    s = sinf(th);
  }
  ctab[idx] = c;
  stab[idx] = s;
}

// ---------------- bf16 GEMM: C(MxN) = A(MxK) * Bt(NxK)^T, f32 out ----------------
#define BM 128
#define BN 128
#define BKS 64

__global__ __launch_bounds__(256) void gemm_bt_k(const ushort* __restrict__ A,
                                                 const ushort* __restrict__ Bt,
                                                 float* __restrict__ C,
                                                 int M, int N, int K) {
  __shared__ __align__(16) ushort As[BM * BKS];
  __shared__ __align__(16) ushort Bs[BN * BKS];
  int tid = threadIdx.x;
  int wave = tid >> 6, lane = tid & 63;
  int lr = lane & 15, lg = lane >> 4;
  int m0 = blockIdx.x * BM, n0 = blockIdx.y * BN;
  int wm = (wave >> 1) * 64, wn = (wave & 1) * 64;

  f32x4 acc[4][4];
  for (int m = 0; m < 4; ++m)
    for (int n = 0; n < 4; ++n)
      acc[m][n] = (f32x4){0.f, 0.f, 0.f, 0.f};

  for (int k0 = 0; k0 < K; k0 += BKS) {
#pragma unroll
    for (int it = 0; it < 4; ++it) {
      int idx = it * 256 + tid;        // 16B chunk id, 1024 total
      int row = idx >> 3;              // 8 chunks per 64-elem row
      int col = (idx & 7) * 8;
      GLOAD_LDS16(A + (size_t)(m0 + row) * K + k0 + col, &As[idx * 8]);
      GLOAD_LDS16(Bt + (size_t)(n0 + row) * K + k0 + col, &Bs[idx * 8]);
    }
    __syncthreads();
#pragma unroll
    for (int kk = 0; kk < 2; ++kk) {
      bf16x8 af[4], bf[4];
#pragma unroll
      for (int m = 0; m < 4; ++m)
        af[m] = *(const bf16x8*)&As[(wm + m * 16 + lr) * BKS + kk * 32 + lg * 8];
#pragma unroll
      for (int n = 0; n < 4; ++n)
        bf[n] = *(const bf16x8*)&Bs[(wn + n * 16 + lr) * BKS + kk * 32 + lg * 8];
#pragma unroll
      for (int m = 0; m < 4; ++m)
#pragma unroll
        for (int n = 0; n < 4; ++n)
          acc[m][n] = __builtin_amdgcn_mfma_f32_16x16x32_bf16(af[m], bf[n], acc[m][n], 0, 0, 0);
    }
    __syncthreads();
  }
#pragma unroll
  for (int m = 0; m < 4; ++m)
#pragma unroll
    for (int n = 0; n < 4; ++n)
#pragma unroll
      for (int r = 0; r < 4; ++r) {
        int row = m0 + wm + m * 16 + lg * 4 + r;
        int col = n0 + wn + n * 16 + lr;
        C[(size_t)row * N + col] = acc[m][n][r];
      }
}

// ---------------- per-(b,t,h): RMSNorm + RoPE + v-mix ----------------
// Q gets ATT_SCALE * log2(e) folded in so attention softmax runs in exp2 domain.
__global__ __launch_bounds__(256) void qkv_post_k(const float* __restrict__ QKVf,
                                                  const float* __restrict__ ve,
                                                  const float* __restrict__ lam,
                                                  const float* __restrict__ ctab,
                                                  const float* __restrict__ stab,
                                                  ushort* __restrict__ Qb,
                                                  ushort* __restrict__ Kb,
                                                  ushort* __restrict__ Vt) {
  int idx = blockIdx.x * 4 + (threadIdx.x >> 6);  // (b*T + t)*NH + h
  int lane = threadIdx.x & 63;
  int h = idx & (NH - 1);
  int bt = idx >> 4;
  int t = bt & (T_SEQ - 1);
  int b = bt >> 11;

  const float* base = QKVf + (size_t)bt * 3072 + h * HDIM + lane;
  float qv = base[0];
  float kv = base[1024];
  float vv = base[2048];

  float sq = qv * qv, sk = kv * kv, sv = vv * vv;
#pragma unroll
  for (int off = 1; off < 64; off <<= 1) {
    sq += __shfl_xor(sq, off);
    sk += __shfl_xor(sk, off);
    sv += __shfl_xor(sv, off);
  }
  qv *= rsqrtf(sq * (1.0f / 64.0f) + 1e-6f);
  kv *= rsqrtf(sk * (1.0f / 64.0f) + 1e-6f);
  vv *= rsqrtf(sv * (1.0f / 64.0f) + 1e-6f);

  int j = lane & 31;
  float c = ctab[t * 32 + j];
  float s = stab[t * 32 + j];
  float qo = __shfl_xor(qv, 32);
  float ko = __shfl_xor(kv, 32);
  float q2 = (lane < 32) ? (qv * c + qo * s) : (qv * c - qo * s);
  float k2 = (lane < 32) ? (kv * c + ko * s) : (kv * c - ko * s);
  float v2 = lam[0] * vv + lam[1] * ve[(size_t)bt * DIMSZ + h * HDIM + lane];

  q2 *= ATT_SCALE * 1.4426950408889634f;  // fold scale + log2(e) for exp2-domain softmax

  int bh = b * NH + h;
  Qb[((size_t)bh * T_SEQ + t) * HDIM + lane] = f2bf(q2);
  Kb[((size_t)bh * T_SEQ + t) * HDIM + lane] = f2bf(k2);
  Vt[((size_t)bh * HDIM + lane) * T_SEQ + t] = f2bf(v2);
}

// ---------------- flash attention: KV-parallel, static-shift softmax ----------------
// Static-shift softmax (no online max: |S*scale*log2e| <= 11.08 after RMSNorm) makes
// KV iterations independent -> the 4 waves of a block split one 16-row q-strip's KV
// range 4 ways (<=8 tiles each) and combine partial O / row-sums via LDS.
// Grid (bh=32, y=128): linear%8 = bh%8 (XCD L2 locality); y ascending maps to qb
// DESCENDING (LPT: heavy blocks dispatch first; 16 block-generations/CU smooth tails).
__global__ __launch_bounds__(256, 4) void attn_k(const ushort* __restrict__ Q,
                                                 const ushort* __restrict__ K,
                                                 const ushort* __restrict__ Vt,
                                                 ushort* __restrict__ Y) {
  int bh = blockIdx.x;          // 0..31
  int y = blockIdx.y;           // 0..127
  int qb = 31 - (y >> 2);       // q-tile, heavy first
  int sub = y & 3;              // 16-row strip within the 64-row q-tile
  int wave = threadIdx.x >> 6, lane = threadIdx.x & 63;
  int lr = lane & 15, lg = lane >> 4;
  int b = bh >> 4, h = bh & 15;

  __shared__ __align__(16) ushort Plds[4][16][72];   // per-wave P tile
  __shared__ __align__(16) float Ored[4][16][68];    // partial O, +4 pad vs bank stride
  __shared__ float lred[4][16];                      // partial row sums

  const ushort* Kbh = K + (size_t)bh * T_SEQ * HDIM;
  const ushort* Vbh = Vt + (size_t)bh * HDIM * T_SEQ;

  int r0 = qb * 64 + sub * 16;
  int nkv = qb + 1;
  int chunk = (nkv + 3) >> 2;
  int kt0 = wave * chunk;
  int kt1 = min(kt0 + chunk, nkv);

  const ushort* Qbase = Q + ((size_t)bh * T_SEQ + r0) * HDIM;
  bf16x8 aq[2];
#pragma unroll
  for (int kk = 0; kk < 2; ++kk)
    aq[kk] = *(const bf16x8*)(Qbase + (size_t)lr * HDIM + kk * 32 + lg * 8);

  // per-lane fragment offsets (elements)
  int koff[8], voff[8];
#pragma unroll
  for (int kk = 0; kk < 2; ++kk)
#pragma unroll
    for (int n = 0; n < 4; ++n) {
      koff[kk * 4 + n] = (n * 16 + lr) * HDIM + kk * 32 + lg * 8;
      voff[kk * 4 + n] = (n * 16 + lr) * T_SEQ + kk * 32 + lg * 8;
    }

  f32x4 o[4];
#pragma unroll
  for (int n = 0; n < 4; ++n) o[n] = (f32x4){0.f, 0.f, 0.f, 0.f};
  float lrow = 0.f;

  if (kt0 < kt1) {
    // preload first K tile of this wave's range
    bf16x8 kc[8];
    const ushort* K0 = Kbh + (size_t)kt0 * 64 * HDIM;
#pragma unroll
    for (int i = 0; i < 8; ++i) kc[i] = *(const bf16x8*)(K0 + koff[i]);

    for (int kb = kt0; kb < kt1; ++kb) {
      // S^T = K . Q^T : lane holds S[q=r0+lr][key = kb*64 + n*16 + lg*4 + r]
      f32x4 s[4];
#pragma unroll
      for (int n = 0; n < 4; ++n) {
        f32x4 a = (f32x4){0.f, 0.f, 0.f, 0.f};
#pragma unroll
        for (int kk = 0; kk < 2; ++kk)
          a = __builtin_amdgcn_mfma_f32_16x16x32_bf16(kc[kk * 4 + n], aq[kk], a, 0, 0, 0);
        s[n] = a;
      }
      // prefetch next K tile (clamped: last iter harmlessly reloads current)
      int nt = (kb + 1 < kt1) ? kb + 1 : kb;
      const ushort* Kn = Kbh + (size_t)nt * 64 * HDIM;
#pragma unroll
      for (int i = 0; i < 8; ++i) kc[i] = *(const bf16x8*)(Kn + koff[i]);
      // V loads for this tile; exp2/pack hides their latency
      bf16x8 vv[8];
      const ushort* Vb = Vbh + kb * 64;
#pragma unroll
      for (int i = 0; i < 8; ++i) vv[i] = *(const bf16x8*)(Vb + voff[i]);

      // causal mask on the diagonal tile
      if (kb == nkv - 1) {
        int qrow = r0 + lr;
        int kb0 = kb * 64 + lg * 4;
#pragma unroll
        for (int n = 0; n < 4; ++n)
#pragma unroll
          for (int r = 0; r < 4; ++r)
            if (kb0 + n * 16 + r > qrow) s[n][r] = -1e30f;
      }
      // P = exp2(S); lane-partial sum; pack to LDS (cvt_pk via paired casts)
      float psum = 0.f;
#pragma unroll
      for (int n = 0; n < 4; ++n) {
        float p0 = exp2f(s[n][0]), p1 = exp2f(s[n][1]);
        float p2 = exp2f(s[n][2]), p3 = exp2f(s[n][3]);
        psum += (p0 + p1) + (p2 + p3);
        uint2 w;
        w.x = pk2(p0, p1);
        w.y = pk2(p2, p3);
        *(uint2*)&Plds[wave][lr][n * 16 + lg * 4] = w;
      }
      lrow += psum;
      // PV: O^T += V^T . P^T
#pragma unroll
      for (int kk = 0; kk < 2; ++kk) {
        bf16x8 ap = *(const bf16x8*)&Plds[wave][lr][kk * 32 + lg * 8];
#pragma unroll
        for (int n = 0; n < 4; ++n)
          o[n] = __builtin_amdgcn_mfma_f32_16x16x32_bf16(vv[kk * 4 + n], ap, o[n], 0, 0, 0);
      }
    }
  }
  // complete this wave's row sums across lg groups (per-q value in all lanes)
  lrow += __shfl_xor(lrow, 16);
  lrow += __shfl_xor(lrow, 32);
  // publish partials
#pragma unroll
  for (int n = 0; n < 4; ++n)
    *(f32x4*)&Ored[wave][lr][n * 16 + lg * 4] = o[n];
  if (lg == 0) lred[wave][lr] = lrow;
  __syncthreads();
  // cross-wave reduce: wave w owns head-dim slice [w*16, w*16+16)
  f32x4 s4 = *(const f32x4*)&Ored[0][lr][wave * 16 + lg * 4];
#pragma unroll
  for (int src = 1; src < 4; ++src) {
    f32x4 t4 = *(const f32x4*)&Ored[src][lr][wave * 16 + lg * 4];
    s4[0] += t4[0]; s4[1] += t4[1]; s4[2] += t4[2]; s4[3] += t4[3];
  }
  float ls = (lred[0][lr] + lred[1][lr]) + (lred[2][lr] + lred[3][lr]);
  float inv = 1.0f / ls;
  int row = r0 + lr;
  uint2 w;
  w.x = pk2(s4[0] * inv, s4[1] * inv);
  w.y = pk2(s4[2] * inv, s4[3] * inv);
  *(uint2*)&Y[((size_t)b * T_SEQ + row) * DIMSZ + h * HDIM + wave * 16 + lg * 4] = w;
}

// ---------------- launch ----------------
extern "C" void kernel_launch(void* const* d_in, const int* in_sizes, int n_in,
                              void* d_out, int out_size, void* d_ws, size_t ws_size,
                              hipStream_t stream) {
  const float* x   = (const float*)d_in[0];
  const float* ve  = (const float*)d_in[1];
  const float* lam = (const float*)d_in[2];
  const float* w   = (const float*)d_in[4];  // (4, 1024, 1024)
  float* out = (float*)d_out;

  char* ws = (char*)d_ws;
  const size_t NTOK = (size_t)NBATCH * T_SEQ;          // 4096
  const size_t nX = NTOK * DIMSZ;                      // 4,194,304
  const size_t nW = 4ull * DIMSZ * DIMSZ;              // 4,194,304

  ushort* Xb   = (ushort*)(ws);                        // 8 MB
  ushort* Wb   = (ushort*)(ws + 8388608);              // 8 MB
  float*  QKVf = (float*)(ws + 16777216);              // 48 MB
  ushort* Qb   = (ushort*)(ws + 67108864);             // 8 MB
  ushort* Kb   = (ushort*)(ws + 75497472);             // 8 MB
  ushort* Vt   = (ushort*)(ws + 83886080);             // 8 MB
  ushort* Yb   = (ushort*)(ws + 92274688);             // 8 MB
  float*  ctab = (float*)(ws + 100663296);             // 256 KB
  float*  stab = (float*)(ws + 100925440);             // 256 KB

  conv_bf16_k<<<(int)(nX / 4 / 256), 256, 0, stream>>>(x, Xb, (int)nX);
  conv_bf16_k<<<(int)(nW / 4 / 256), 256, 0, stream>>>(w, Wb, (int)nW);
  rope_tab_k<<<(T_SEQ * 32) / 256, 256, 0, stream>>>(ctab, stab);

  // QKV: (4096 x 3072) = Xb (4096x1024) @ Wb[0:3072]^T
  gemm_bt_k<<<dim3(4096 / BM, 3072 / BN), 256, 0, stream>>>(Xb, Wb, QKVf, 4096, 3072, 1024);

  qkv_post_k<<<(int)(NTOK * NH / 4), 256, 0, stream>>>(QKVf, ve, lam, ctab, stab, Qb, Kb, Vt);

  attn_k<<<dim3(NBATCH * NH, 128), 256, 0, stream>>>(Qb, Kb, Vt, Yb);

  // out: (4096 x 1024) = Yb @ W3^T, f32 straight to d_out
  gemm_bt_k<<<dim3(4096 / BM, 1024 / BN), 256, 0, stream>>>(Yb, Wb + 3ull * DIMSZ * DIMSZ, out, 4096, 1024, 1024);
}

// Round 6
// 232.361 us; speedup vs baseline: 1.1961x; 1.1961x over previous
//
#include <hip/hip_runtime.h>
#include <hip/hip_bf16.h>
#include <stdint.h>

#define T_SEQ 2048
#define DIMSZ 1024
#define NH    16
#define HDIM  64
#define NBATCH 2
#define ATT_SCALE 0.12f

typedef __attribute__((ext_vector_type(8))) __bf16 bf16x8;
typedef __attribute__((ext_vector_type(4))) float f32x4;

#define GLOAD_LDS16(gp, lp)                                                            \
  __builtin_amdgcn_global_load_lds((const __attribute__((address_space(1))) void*)(gp),\
                                   (__attribute__((address_space(3))) void*)(lp),      \
                                   16, 0, 0)

__device__ __forceinline__ ushort f2bf(float f) {
  union { float f; uint32_t u; } v; v.f = f;
  uint32_t u = v.u;
  uint32_t r = (u + 0x7FFFu + ((u >> 16) & 1u)) >> 16;
  return (ushort)r;
}

__device__ __forceinline__ float bf2f(ushort h) {
  union { float f; uint32_t u; } v;
  v.u = ((uint32_t)h) << 16;
  return v.f;
}

// paired f32->bf16 (compiler fuses into v_cvt_pk_bf16_f32)
__device__ __forceinline__ uint32_t pk2(float a, float b) {
  union { __hip_bfloat162 h; uint32_t u; } cv;
  cv.h = __hip_bfloat162(__float2bfloat16(a), __float2bfloat16(b));
  return cv.u;
}

// ---------------- f32 -> bf16 convert (vectorized) ----------------
__global__ __launch_bounds__(256) void conv_bf16_k(const float* __restrict__ in,
                                                   ushort* __restrict__ out, int n) {
  int i = (blockIdx.x * 256 + threadIdx.x) * 4;
  if (i >= n) return;
  float4 v = *(const float4*)(in + i);
  ushort4 o;
  o.x = f2bf(v.x); o.y = f2bf(v.y); o.z = f2bf(v.z); o.w = f2bf(v.w);
  *(ushort4*)(out + i) = o;
}

// ---------------- RoPE tables: cos/sin (T x 32) ----------------
__global__ __launch_bounds__(256) void rope_tab_k(float* __restrict__ ctab,
                                                  float* __restrict__ stab) {
  int idx = blockIdx.x * 256 + threadIdx.x;  // t*32 + j
  if (idx >= T_SEQ * 32) return;
  int j = idx & 31, t = idx >> 5;
  float c = 1.f, s = 0.f;
  if (j < 16) {
    float inv = powf(1024.0f, -(float)j / 15.0f);  // (1/1024)^(j/15)
    float th = (float)t * inv;
    c = cosf(th);
    s = sinf(th);
  }
  ctab[idx] = c;
  stab[idx] = s;
}

// ---------------- bf16 GEMM: C(MxN) = A(MxK) * Bt(NxK)^T ----------------
#define BM 128
#define BN 128
#define BKS 64

template <typename OT>
__global__ __launch_bounds__(256) void gemm_bt_k(const ushort* __restrict__ A,
                                                 const ushort* __restrict__ Bt,
                                                 OT* __restrict__ C,
                                                 int M, int N, int K) {
  __shared__ __align__(16) ushort As[BM * BKS];
  __shared__ __align__(16) ushort Bs[BN * BKS];
  int tid = threadIdx.x;
  int wave = tid >> 6, lane = tid & 63;
  int lr = lane & 15, lg = lane >> 4;
  int m0 = blockIdx.x * BM, n0 = blockIdx.y * BN;
  int wm = (wave >> 1) * 64, wn = (wave & 1) * 64;

  f32x4 acc[4][4];
  for (int m = 0; m < 4; ++m)
    for (int n = 0; n < 4; ++n)
      acc[m][n] = (f32x4){0.f, 0.f, 0.f, 0.f};

  for (int k0 = 0; k0 < K; k0 += BKS) {
#pragma unroll
    for (int it = 0; it < 4; ++it) {
      int idx = it * 256 + tid;        // 16B chunk id, 1024 total
      int row = idx >> 3;              // 8 chunks per 64-elem row
      int col = (idx & 7) * 8;
      GLOAD_LDS16(A + (size_t)(m0 + row) * K + k0 + col, &As[idx * 8]);
      GLOAD_LDS16(Bt + (size_t)(n0 + row) * K + k0 + col, &Bs[idx * 8]);
    }
    __syncthreads();
#pragma unroll
    for (int kk = 0; kk < 2; ++kk) {
      bf16x8 af[4], bf[4];
#pragma unroll
      for (int m = 0; m < 4; ++m)
        af[m] = *(const bf16x8*)&As[(wm + m * 16 + lr) * BKS + kk * 32 + lg * 8];
#pragma unroll
      for (int n = 0; n < 4; ++n)
        bf[n] = *(const bf16x8*)&Bs[(wn + n * 16 + lr) * BKS + kk * 32 + lg * 8];
#pragma unroll
      for (int m = 0; m < 4; ++m)
#pragma unroll
        for (int n = 0; n < 4; ++n)
          acc[m][n] = __builtin_amdgcn_mfma_f32_16x16x32_bf16(af[m], bf[n], acc[m][n], 0, 0, 0);
    }
    __syncthreads();
  }
#pragma unroll
  for (int m = 0; m < 4; ++m)
#pragma unroll
    for (int n = 0; n < 4; ++n)
#pragma unroll
      for (int r = 0; r < 4; ++r) {
        int row = m0 + wm + m * 16 + lg * 4 + r;
        int col = n0 + wn + n * 16 + lr;
        if constexpr (sizeof(OT) == 2)
          C[(size_t)row * N + col] = (OT)f2bf(acc[m][n][r]);
        else
          C[(size_t)row * N + col] = (OT)acc[m][n][r];
      }
}

// ---------------- per-(b,t,h): RMSNorm + RoPE + v-mix (bf16 input) ----------------
// Q gets ATT_SCALE * log2(e) folded in so attention softmax runs in exp2 domain.
__global__ __launch_bounds__(256) void qkv_post_k(const ushort* __restrict__ QKVb,
                                                  const float* __restrict__ ve,
                                                  const float* __restrict__ lam,
                                                  const float* __restrict__ ctab,
                                                  const float* __restrict__ stab,
                                                  ushort* __restrict__ Qb,
                                                  ushort* __restrict__ Kb,
                                                  ushort* __restrict__ Vt) {
  int idx = blockIdx.x * 4 + (threadIdx.x >> 6);  // (b*T + t)*NH + h
  int lane = threadIdx.x & 63;
  int h = idx & (NH - 1);
  int bt = idx >> 4;
  int t = bt & (T_SEQ - 1);
  int b = bt >> 11;

  const ushort* base = QKVb + (size_t)bt * 3072 + h * HDIM + lane;
  float qv = bf2f(base[0]);
  float kv = bf2f(base[1024]);
  float vv = bf2f(base[2048]);

  float sq = qv * qv, sk = kv * kv, sv = vv * vv;
#pragma unroll
  for (int off = 1; off < 64; off <<= 1) {
    sq += __shfl_xor(sq, off);
    sk += __shfl_xor(sk, off);
    sv += __shfl_xor(sv, off);
  }
  qv *= rsqrtf(sq * (1.0f / 64.0f) + 1e-6f);
  kv *= rsqrtf(sk * (1.0f / 64.0f) + 1e-6f);
  vv *= rsqrtf(sv * (1.0f / 64.0f) + 1e-6f);

  int j = lane & 31;
  float c = ctab[t * 32 + j];
  float s = stab[t * 32 + j];
  float qo = __shfl_xor(qv, 32);
  float ko = __shfl_xor(kv, 32);
  float q2 = (lane < 32) ? (qv * c + qo * s) : (qv * c - qo * s);
  float k2 = (lane < 32) ? (kv * c + ko * s) : (kv * c - ko * s);
  float v2 = lam[0] * vv + lam[1] * ve[(size_t)bt * DIMSZ + h * HDIM + lane];

  q2 *= ATT_SCALE * 1.4426950408889634f;  // fold scale + log2(e) for exp2-domain softmax

  int bh = b * NH + h;
  Qb[((size_t)bh * T_SEQ + t) * HDIM + lane] = f2bf(q2);
  Kb[((size_t)bh * T_SEQ + t) * HDIM + lane] = f2bf(k2);
  Vt[((size_t)bh * HDIM + lane) * T_SEQ + t] = f2bf(v2);
}

// ---------------- flash attention: R3 structure + static-shift softmax ----------------
// Grid (bh=32, pair=16), 4 waves, each block does q-tile `pair` then `31-pair`:
// uniform 33 KV iterations per wave, no barriers, schedule-independent balance.
// Static-shift softmax: |S*scale*log2e| <= 11.08 after RMSNorm -> P = exp2(S) directly;
// NO online max, NO rescale, NO cross-lane ops in the loop (epilogue-only reduce).
__global__ __launch_bounds__(256, 2) void attn_k(const ushort* __restrict__ Q,
                                                 const ushort* __restrict__ K,
                                                 const ushort* __restrict__ Vt,
                                                 ushort* __restrict__ Y) {
  int bh = blockIdx.x;    // 0..31 -> linear%8 = bh%8 (XCD L2 locality)
  int pair = blockIdx.y;  // 0..15
  int wave = threadIdx.x >> 6, lane = threadIdx.x & 63;
  int lr = lane & 15, lg = lane >> 4;
  int b = bh >> 4, h = bh & 15;

  __shared__ __align__(16) ushort Plds[4][16][72];  // per-wave P tile, no conflicts at 2-way

  const ushort* Kbh = K + (size_t)bh * T_SEQ * HDIM;
  const ushort* Vbh = Vt + (size_t)bh * HDIM * T_SEQ;

  for (int halfi = 0; halfi < 2; ++halfi) {
    int qb = halfi ? (31 - pair) : pair;
    int r0 = qb * 64 + wave * 16;
    int nkv = qb + 1;

    const ushort* Qbase = Q + ((size_t)bh * T_SEQ + r0) * HDIM;
    bf16x8 aq[2];
#pragma unroll
    for (int kk = 0; kk < 2; ++kk)
      aq[kk] = *(const bf16x8*)(Qbase + (size_t)lr * HDIM + kk * 32 + lg * 8);

    f32x4 o[4];
#pragma unroll
    for (int n = 0; n < 4; ++n) o[n] = (f32x4){0.f, 0.f, 0.f, 0.f};
    float lrow = 0.f;  // lane-partial row sum (16 keys/iter); reduced in epilogue

    // preload K block 0
    bf16x8 kc[8];
#pragma unroll
    for (int kk = 0; kk < 2; ++kk)
#pragma unroll
      for (int n = 0; n < 4; ++n)
        kc[kk * 4 + n] = *(const bf16x8*)(Kbh + (size_t)(n * 16 + lr) * HDIM + kk * 32 + lg * 8);

    for (int kb = 0; kb < nkv; ++kb) {
      int s0 = kb * 64;
      // S^T = K . Q^T : lane holds S[q=r0+lr][key = s0 + n*16 + lg*4 + r]
      f32x4 s[4];
#pragma unroll
      for (int n = 0; n < 4; ++n) {
        f32x4 a = (f32x4){0.f, 0.f, 0.f, 0.f};
#pragma unroll
        for (int kk = 0; kk < 2; ++kk)
          a = __builtin_amdgcn_mfma_f32_16x16x32_bf16(kc[kk * 4 + n], aq[kk], a, 0, 0, 0);
        s[n] = a;
      }
      // guarded prefetch of next K block (WAR-safe; hidden under exp2 + PV)
      if (kb + 1 < nkv) {
        const ushort* Kn = Kbh + (size_t)(s0 + 64) * HDIM;
#pragma unroll
        for (int kk = 0; kk < 2; ++kk)
#pragma unroll
          for (int n = 0; n < 4; ++n)
            kc[kk * 4 + n] = *(const bf16x8*)(Kn + (size_t)(n * 16 + lr) * HDIM + kk * 32 + lg * 8);
      }
      // issue V loads now; exp2/pack hides their latency
      bf16x8 vv[8];
#pragma unroll
      for (int kk = 0; kk < 2; ++kk)
#pragma unroll
        for (int n = 0; n < 4; ++n)
          vv[kk * 4 + n] = *(const bf16x8*)(Vbh + (size_t)(n * 16 + lr) * T_SEQ + s0 + kk * 32 + lg * 8);

      // causal mask on the diagonal block
      if (kb == nkv - 1) {
        int qrow = r0 + lr;
        int kb0 = s0 + lg * 4;
#pragma unroll
        for (int n = 0; n < 4; ++n)
#pragma unroll
          for (int r = 0; r < 4; ++r)
            if (kb0 + n * 16 + r > qrow) s[n][r] = -1e30f;
      }
      // P = exp2(S)  (static shift: bounded by 2^11.1); lane-partial sum; pack
      float psum = 0.f;
#pragma unroll
      for (int n = 0; n < 4; ++n) {
        float p0 = exp2f(s[n][0]), p1 = exp2f(s[n][1]);
        float p2 = exp2f(s[n][2]), p3 = exp2f(s[n][3]);
        psum += (p0 + p1) + (p2 + p3);
        uint2 w;
        w.x = pk2(p0, p1);
        w.y = pk2(p2, p3);
        *(uint2*)&Plds[wave][lr][n * 16 + lg * 4] = w;
      }
      lrow += psum;
      // PV: O^T += V^T . P^T
#pragma unroll
      for (int kk = 0; kk < 2; ++kk) {
        bf16x8 ap = *(const bf16x8*)&Plds[wave][lr][kk * 32 + lg * 8];
#pragma unroll
        for (int n = 0; n < 4; ++n)
          o[n] = __builtin_amdgcn_mfma_f32_16x16x32_bf16(vv[kk * 4 + n], ap, o[n], 0, 0, 0);
      }
    }
    // epilogue: complete row sum across lg groups, normalize, write
    lrow += __shfl_xor(lrow, 16);
    lrow += __shfl_xor(lrow, 32);
    float inv = 1.0f / lrow;
    int row = r0 + lr;
#pragma unroll
    for (int n = 0; n < 4; ++n) {
      uint2 w;
      w.x = pk2(o[n][0] * inv, o[n][1] * inv);
      w.y = pk2(o[n][2] * inv, o[n][3] * inv);
      *(uint2*)&Y[((size_t)b * T_SEQ + row) * DIMSZ + h * HDIM + n * 16 + lg * 4] = w;
    }
  }
}

// ---------------- launch ----------------
extern "C" void kernel_launch(void* const* d_in, const int* in_sizes, int n_in,
                              void* d_out, int out_size, void* d_ws, size_t ws_size,
                              hipStream_t stream) {
  const float* x   = (const float*)d_in[0];
  const float* ve  = (const float*)d_in[1];
  const float* lam = (const float*)d_in[2];
  const float* w   = (const float*)d_in[4];  // (4, 1024, 1024)
  float* out = (float*)d_out;

  char* ws = (char*)d_ws;
  const size_t NTOK = (size_t)NBATCH * T_SEQ;          // 4096
  const size_t nX = NTOK * DIMSZ;                      // 4,194,304
  const size_t nW = 4ull * DIMSZ * DIMSZ;              // 4,194,304

  ushort* Xb   = (ushort*)(ws);                        // 8 MB  @ 0
  ushort* Wb   = (ushort*)(ws + 8388608);              // 8 MB  @ 8M
  ushort* QKVb = (ushort*)(ws + 16777216);             // 24 MB @ 16M (bf16 now)
  ushort* Qb   = (ushort*)(ws + 50331648);             // 8 MB  @ 48M
  ushort* Kb   = (ushort*)(ws + 58720256);             // 8 MB  @ 56M
  ushort* Vt   = (ushort*)(ws + 67108864);             // 8 MB  @ 64M
  ushort* Yb   = (ushort*)(ws + 75497472);             // 8 MB  @ 72M
  float*  ctab = (float*)(ws + 83886080);              // 256 KB @ 80M
  float*  stab = (float*)(ws + 84148224);              // 256 KB

  conv_bf16_k<<<(int)(nX / 4 / 256), 256, 0, stream>>>(x, Xb, (int)nX);
  conv_bf16_k<<<(int)(nW / 4 / 256), 256, 0, stream>>>(w, Wb, (int)nW);
  rope_tab_k<<<(T_SEQ * 32) / 256, 256, 0, stream>>>(ctab, stab);

  // QKV: (4096 x 3072) = Xb (4096x1024) @ Wb[0:3072]^T, bf16 out
  gemm_bt_k<ushort><<<dim3(4096 / BM, 3072 / BN), 256, 0, stream>>>(Xb, Wb, QKVb, 4096, 3072, 1024);

  qkv_post_k<<<(int)(NTOK * NH / 4), 256, 0, stream>>>(QKVb, ve, lam, ctab, stab, Qb, Kb, Vt);

  attn_k<<<dim3(NBATCH * NH, 16), 256, 0, stream>>>(Qb, Kb, Vt, Yb);

  // out: (4096 x 1024) = Yb @ W3^T, f32 straight to d_out
  gemm_bt_k<float><<<dim3(4096 / BM, 1024 / BN), 256, 0, stream>>>(Yb, Wb + 3ull * DIMSZ * DIMSZ, out, 4096, 1024, 1024);
}